// Round 16
// baseline (85.019 us; speedup 1.0000x reference)
//
#include <hip/hip_runtime.h>

#define BB   64
#define TT   200
#define NIN  128
#define NN   2048
#define NOUT 20

#define S    8      // speculation window (TT = 25 * S)
#define NWIN 25
#define ACAP 64     // spec spike list capacity per step
#define BCAP 128    // replay spike list capacity

typedef __attribute__((ext_vector_type(8))) short short8;
typedef __attribute__((ext_vector_type(4))) float f32x4;
typedef __attribute__((ext_vector_type(4))) _Float16 h16x4;

// ---- bf16 split: x = hi + lo + eps, |eps| <= 2^-18 |x| ----------------------
__device__ __forceinline__ void bf16split(float x, ushort& h, ushort& l) {
    unsigned u = __float_as_uint(x);
    unsigned hb = (u + 0x7FFFu + ((u >> 16) & 1u)) >> 16;
    h = (ushort)hb;
    float xh = __uint_as_float(hb << 16);
    float xl = x - xh;                      // exact
    unsigned v = __float_as_uint(xl);
    l = (ushort)((v + 0x7FFFu + ((v >> 16) & 1u)) >> 16);
}

// ---- merged pre-kernel: split+repack A and B^T into MFMA-fragment order ----
// Blocks 0..799: Ap [row_blk=800][kc=4][hl=2][lane=64][8] from inputs.
// Blocks 800..927: Bp [n_blk=128][kc=4][hl=2][lane=64][8] from w_in (transp.)
__global__ __launch_bounds__(256) void repack_ab(
    const float* __restrict__ X, const float* __restrict__ W,
    ushort* __restrict__ Ap, ushort* __restrict__ Bp)
{
    const int tid  = threadIdx.x;
    const int kc   = tid >> 6;
    const int lane = tid & 63;
    const int lr   = lane & 15, lg = lane >> 4;

    float f[8];
    ushort* dst;
    if (blockIdx.x < 800) {
        const int blk = blockIdx.x;         // row_blk 0..799
        const float* src = X + (size_t)(blk * 16 + lr) * NIN + kc * 32 + lg * 8;
        *(float4*)(f)     = *(const float4*)(src);
        *(float4*)(f + 4) = *(const float4*)(src + 4);
        dst = Ap + (size_t)(blk * 4 + kc) * 1024 + lane * 8;
    } else {
        const int blk = blockIdx.x - 800;   // n_blk 0..127
        const float* src = W + (size_t)(kc * 32 + lg * 8) * NN + blk * 16 + lr;
        #pragma unroll
        for (int j = 0; j < 8; ++j) f[j] = src[(size_t)j * NN];
        dst = Bp + (size_t)(blk * 4 + kc) * 1024 + lane * 8;
    }

    short8 hv, lv;
    #pragma unroll
    for (int j = 0; j < 8; ++j) {
        ushort h, l;
        bf16split(f[j], h, l);
        hv[j] = (short)h; lv[j] = (short)l;
    }
    *(short8*)(dst)       = hv;
    *(short8*)(dst + 512) = lv;
}

// ---- MFMA GEMM: single-buffered 32KB LDS stage, 4 blocks/CU ----------------
// h1 = Ah*Bh + Ah*Bl + Al*Bh  (verified product set / chain order — bit-exact)
// NEW (this round): occupancy probe. 32KB single-buffer stage + min 4
// waves/EU -> 4 blocks/CU (16 waves/CU, 2x R10). In-block stage latency is
// exposed (2 barriers/kc) but cross-block pipelining hides it — isolates the
// occupancy axis that R13 confounded with tile size.
__global__ __launch_bounds__(256, 4) void h1_mfma(
    const ushort* __restrict__ Ap, const ushort* __restrict__ Bp,
    _Float16* __restrict__ C)
{
    __shared__ ushort sbuf[16][1024];      // [side*8+chunk][hl*512+lane*8]

    const int l   = blockIdx.y * gridDim.x + blockIdx.x;  // 0..1599
    const int nl  = (l & 7) * 200 + (l >> 3);             // bijective XCD chunk
    const int bx  = nl & 15, by = nl >> 4;

    const int tid  = threadIdx.x;
    const int w_   = tid >> 6, lane = tid & 63;
    const int lr   = lane & 15, lg = lane >> 4;
    const int m0   = by * 128, n0 = bx * 128;
    const int wr   = (w_ >> 1) * 64, wc = (w_ & 1) * 64;

    const ushort* pAs = Ap + (size_t)(m0 >> 4) * 4096;    // row_blk stride 4096
    const ushort* pBs = Bp + (size_t)(n0 >> 4) * 4096;

    // wave w_ stages (chunk,hl) pairs idx = w_*8 .. w_*8+7 of 32 total
#define STAGE(kc)                                                            \
    do {                                                                     \
        _Pragma("unroll")                                                    \
        for (int i_ = 0; i_ < 8; ++i_) {                                     \
            const int idx_   = w_ * 8 + i_;                                  \
            const int side_  = idx_ >> 4;                                    \
            const int chunk_ = (idx_ >> 1) & 7;                              \
            const int hl_    = idx_ & 1;                                     \
            const ushort* g_ = (side_ ? pBs : pAs) + chunk_ * 4096           \
                               + (kc) * 1024 + hl_ * 512 + lane * 8;         \
            ushort* d_ = &sbuf[idx_ >> 1][hl_ * 512];                        \
            __builtin_amdgcn_global_load_lds(                                \
                (const __attribute__((address_space(1))) void*)g_,           \
                (__attribute__((address_space(3))) void*)d_, 16, 0, 0);      \
        }                                                                    \
    } while (0)

    f32x4 acc[4][4];
    const f32x4 z = {0.f, 0.f, 0.f, 0.f};
    #pragma unroll
    for (int rb = 0; rb < 4; ++rb)
        #pragma unroll
        for (int cb = 0; cb < 4; ++cb) acc[rb][cb] = z;

    const int ar = wr >> 4;        // A chunk base (0 or 4)
    const int br = 8 + (wc >> 4);  // B chunk base (8 or 12)

    #pragma unroll
    for (int kc = 0; kc < 4; ++kc) {
        STAGE(kc);
        __syncthreads();    // drains vmcnt: stage(kc) complete

        short8 fah[4], fal[4], fbh[4], fbl[4];
        #pragma unroll
        for (int rb = 0; rb < 4; ++rb) {
            fah[rb] = *(const short8*)(&sbuf[ar + rb][lane * 8]);
            fal[rb] = *(const short8*)(&sbuf[ar + rb][512 + lane * 8]);
        }
        #pragma unroll
        for (int cb = 0; cb < 4; ++cb) {
            fbh[cb] = *(const short8*)(&sbuf[br + cb][lane * 8]);
            fbl[cb] = *(const short8*)(&sbuf[br + cb][512 + lane * 8]);
        }
        #pragma unroll
        for (int rb = 0; rb < 4; ++rb)
            #pragma unroll
            for (int cb = 0; cb < 4; ++cb) {
                acc[rb][cb] = __builtin_amdgcn_mfma_f32_16x16x32_bf16(
                    fbh[cb], fah[rb], acc[rb][cb], 0, 0, 0);
                acc[rb][cb] = __builtin_amdgcn_mfma_f32_16x16x32_bf16(
                    fbl[cb], fah[rb], acc[rb][cb], 0, 0, 0);
                acc[rb][cb] = __builtin_amdgcn_mfma_f32_16x16x32_bf16(
                    fbh[cb], fal[rb], acc[rb][cb], 0, 0, 0);
            }
        if (kc < 3) __syncthreads();   // all reads done before next stage
    }
#undef STAGE

    #pragma unroll
    for (int rb = 0; rb < 4; ++rb) {
        _Float16* Crow = C + (size_t)(m0 + wr + rb * 16 + lr) * NN
                           + n0 + wc + lg * 4;
        #pragma unroll
        for (int cb = 0; cb < 4; ++cb) {
            h16x4 hv;
            hv[0] = (_Float16)acc[rb][cb][0];
            hv[1] = (_Float16)acc[rb][cb][1];
            hv[2] = (_Float16)acc[rb][cb][2];
            hv[3] = (_Float16)acc[rb][cb][3];
            *(h16x4*)(Crow + cb * 16) = hv;
        }
    }
}

// ---------------- Phase 2+3: speculative windowed scan (R10 verbatim) --------
// 512 thr x 4 neurons, S=8. Slim dirty path (1-barrier cnt==0 steps, t* w-row
// prefetch). Verified 43-46us / VGPR 88.
__global__ __launch_bounds__(512) void snn_scan(
    const _Float16* __restrict__ h1, const float* __restrict__ w,
    const float* __restrict__ w_signs, const float* __restrict__ pvec,
    const float* __restrict__ w_out, float* __restrict__ out)
{
    const int b   = blockIdx.x;
    const int tid = threadIdx.x;
    const int n0  = tid << 2;

    __shared__ int   s_amask[2];
    __shared__ int   s_acnt[2][S];
    __shared__ int   s_aidx[2][S][ACAP];
    __shared__ float s_aval[2][S][ACAP];
    __shared__ int   s_bcnt[2];
    __shared__ int   s_bidx[2][BCAP];
    __shared__ float s_bval[2][BCAP];

    if (tid < 2) { s_amask[tid] = 0; s_bcnt[tid] = 0; }
    if (tid < 2 * S) ((int*)s_acnt)[tid] = 0;

    float4 mem = {0.f,0.f,0.f,0.f}, wp = {0.f,0.f,0.f,0.f};
    const float4 p4 = *(const float4*)(pvec + n0);
    const float4 sg = *(const float4*)(w_signs + n0);
    float4 depr;
    depr.x = (p4.x < 0.f) ? 1.f : 0.f;  depr.y = (p4.y < 0.f) ? 1.f : 0.f;
    depr.z = (p4.z < 0.f) ? 1.f : 0.f;  depr.w = (p4.w < 0.f) ? 1.f : 0.f;

    const float P99[S] = {1.0f, 0.99f, 0.9801f, 0.970299f, 0.96059601f,
                          0.9509900499f, 0.941480149401f, 0.93206534790699f};
    const float P99_8 = 0.9227446944279201f;

    const _Float16* hb = h1 + (size_t)b * TT * NN + n0;
    float* outb = out + (size_t)b * TT * NOUT + tid;   // used only if tid<20
    float o2 = 0.f;

    h16x4 PA[S], PB[S];
    #pragma unroll
    for (int j = 0; j < S; ++j) PA[j] = *(const h16x4*)(hb + (size_t)j * NN);
    __syncthreads();   // LDS init visible

#define RAWBAR()                                              \
    do { asm volatile("s_waitcnt lgkmcnt(0)" ::: "memory");   \
         __builtin_amdgcn_s_barrier();                        \
         asm volatile("" ::: "memory"); } while (0)

#define CVT4(v) { (float)(v)[0], (float)(v)[1], (float)(v)[2], (float)(v)[3] }

    auto window = [&](h16x4 (&Pc)[S], h16x4 (&Pf)[S], int wnd) {
        const int p  = wnd & 1;
        const int t0 = wnd * S;
        const float4 memB = mem, wpB = wp;

        // ---- slim speculative pass: syn = 0, wp frozen, no barriers ----
        #pragma unroll
        for (int j = 0; j < S; ++j) {
            const float4 a = CVT4(Pc[j]);
            int tp = t0 + j + S; if (tp > TT - 1) tp = TT - 1;
            Pf[j] = *(const h16x4*)(hb + (size_t)tp * NN);   // depth-1 fetch

            // spike test on PRE-update mem (reference semantics)
            const float mx = fmaxf(fmaxf(mem.x, mem.y), fmaxf(mem.z, mem.w));
            if (__builtin_expect(mx > 1.f, 0)) {
                const bool f0 = mem.x > 1.f, f1 = mem.y > 1.f,
                           f2 = mem.z > 1.f, f3 = mem.w > 1.f;
                atomicOr(&s_amask[p], 1 << j);
                if (f0) { int k = atomicAdd(&s_acnt[p][j], 1);
                          if (k < ACAP) { s_aidx[p][j][k] = n0;
                                          s_aval[p][j][k] = (1.f + wp.x * P99[j]) * sg.x; } }
                if (f1) { int k = atomicAdd(&s_acnt[p][j], 1);
                          if (k < ACAP) { s_aidx[p][j][k] = n0 + 1;
                                          s_aval[p][j][k] = (1.f + wp.y * P99[j]) * sg.y; } }
                if (f2) { int k = atomicAdd(&s_acnt[p][j], 1);
                          if (k < ACAP) { s_aidx[p][j][k] = n0 + 2;
                                          s_aval[p][j][k] = (1.f + wp.z * P99[j]) * sg.z; } }
                if (f3) { int k = atomicAdd(&s_acnt[p][j], 1);
                          if (k < ACAP) { s_aidx[p][j][k] = n0 + 3;
                                          s_aval[p][j][k] = (1.f + wp.w * P99[j]) * sg.w; } }
                mem.x = fmaf(0.9f, mem.x, a.x) - (f0 ? 1.f : 0.f);
                mem.y = fmaf(0.9f, mem.y, a.y) - (f1 ? 1.f : 0.f);
                mem.z = fmaf(0.9f, mem.z, a.z) - (f2 ? 1.f : 0.f);
                mem.w = fmaf(0.9f, mem.w, a.w) - (f3 ? 1.f : 0.f);
            } else {
                mem.x = fmaf(0.9f, mem.x, a.x);
                mem.y = fmaf(0.9f, mem.y, a.y);
                mem.z = fmaf(0.9f, mem.z, a.z);
                mem.w = fmaf(0.9f, mem.w, a.w);
            }
        }

        RAWBAR();                    // no vmcnt drain: prefetch stays in flight
        const int mask = s_amask[p];

        if (__builtin_expect(mask == 0, 1)) {   // ---- clean window ----
            wp.x *= P99_8; wp.y *= P99_8; wp.z *= P99_8; wp.w *= P99_8;
            if (tid < NOUT) {
                #pragma unroll
                for (int j = 0; j < S; ++j) {
                    o2 = 0.9f * o2;
                    outb[(size_t)(t0 + j) * NOUT] = o2;
                }
            }
            return;
        }

        // ---- dirty window: rollback + exact replay (slim sync) ----
        const int tstar = __ffs(mask) - 1;

        // prefetch t* w-rows early: list is exact & complete; hide gather
        // latency under the j<t* register replay. (cnt is block-uniform.)
        int cntS = s_acnt[p][tstar]; if (cntS > ACAP) cntS = ACAP;
        int   pidx[4];
        float pval[4];
        float4 wpre[4];
        #pragma unroll
        for (int m_ = 0; m_ < 4; ++m_) {
            if (m_ < cntS) {
                pidx[m_] = s_aidx[p][tstar][m_];
                pval[m_] = s_aval[p][tstar][m_];
                wpre[m_] = *(const float4*)(w + (size_t)pidx[m_] * NN + n0);
            }
        }

        mem = memB; wp = wpB;
        #pragma unroll
        for (int j = 0; j < S; ++j) {
            const float4 a = CVT4(Pc[j]);
            if (j < tstar) {          // certified spike-free
                mem.x = fmaf(0.9f, mem.x, a.x);
                mem.y = fmaf(0.9f, mem.y, a.y);
                mem.z = fmaf(0.9f, mem.z, a.z);
                mem.w = fmaf(0.9f, mem.w, a.w);
                wp.x *= 0.99f; wp.y *= 0.99f; wp.z *= 0.99f; wp.w *= 0.99f;
                if (tid < NOUT) { o2 = 0.9f * o2;
                                  outb[(size_t)(t0 + j) * NOUT] = o2; }
            } else if (j == tstar) {  // spec list at t* is exact & complete
                const bool f0 = mem.x > 1.f, f1 = mem.y > 1.f,   // pre-update
                           f2 = mem.z > 1.f, f3 = mem.w > 1.f;
                float4 syn = {0.f,0.f,0.f,0.f};
                #pragma unroll
                for (int m_ = 0; m_ < 4; ++m_) {
                    if (m_ < cntS) {
                        syn.x = fmaf(pval[m_], fabsf(wpre[m_].x), syn.x);
                        syn.y = fmaf(pval[m_], fabsf(wpre[m_].y), syn.y);
                        syn.z = fmaf(pval[m_], fabsf(wpre[m_].z), syn.z);
                        syn.w = fmaf(pval[m_], fabsf(wpre[m_].w), syn.w);
                    }
                }
                for (int m = 4; m < cntS; ++m) {
                    const int nm = s_aidx[p][tstar][m];
                    const float vm = s_aval[p][tstar][m];
                    const float4 wr = *(const float4*)(w + (size_t)nm * NN + n0);
                    syn.x = fmaf(vm, fabsf(wr.x), syn.x);
                    syn.y = fmaf(vm, fabsf(wr.y), syn.y);
                    syn.z = fmaf(vm, fabsf(wr.z), syn.z);
                    syn.w = fmaf(vm, fabsf(wr.w), syn.w);
                }
                if (tid < NOUT) {
                    float c = 0.f;
                    for (int m = 0; m < cntS; ++m)
                        c += w_out[(size_t)s_aidx[p][tstar][m] * NOUT + tid];
                    o2 = 0.9f * o2 + c;
                    outb[(size_t)(t0 + j) * NOUT] = o2;
                }
                mem.x = fmaf(0.9f, mem.x, a.x) + syn.x - (f0 ? 1.f : 0.f);
                mem.y = fmaf(0.9f, mem.y, a.y) + syn.y - (f1 ? 1.f : 0.f);
                mem.z = fmaf(0.9f, mem.z, a.z) + syn.z - (f2 ? 1.f : 0.f);
                mem.w = fmaf(0.9f, mem.w, a.w) + syn.w - (f3 ? 1.f : 0.f);
                wp.x = f0 ? 0.99f*wp.x + p4.x*(1.f + depr.x*wp.x) : 0.99f*wp.x;
                wp.y = f1 ? 0.99f*wp.y + p4.y*(1.f + depr.y*wp.y) : 0.99f*wp.y;
                wp.z = f2 ? 0.99f*wp.z + p4.z*(1.f + depr.z*wp.z) : 0.99f*wp.z;
                wp.w = f3 ? 0.99f*wp.w + p4.w*(1.f + depr.w*wp.w) : 0.99f*wp.w;
            } else {                  // slow step: 1 barrier; exchange only if
                                      // spikes actually landed this step
                const int par = j & 1;
                const bool f0 = mem.x > 1.f, f1 = mem.y > 1.f,   // pre-update
                           f2 = mem.z > 1.f, f3 = mem.w > 1.f;
                if (f0 | f1 | f2 | f3) {
                    if (f0) { int k = atomicAdd(&s_bcnt[par], 1); if (k < BCAP) {
                              s_bidx[par][k] = n0;     s_bval[par][k] = (1.f + wp.x) * sg.x; } }
                    if (f1) { int k = atomicAdd(&s_bcnt[par], 1); if (k < BCAP) {
                              s_bidx[par][k] = n0 + 1; s_bval[par][k] = (1.f + wp.y) * sg.y; } }
                    if (f2) { int k = atomicAdd(&s_bcnt[par], 1); if (k < BCAP) {
                              s_bidx[par][k] = n0 + 2; s_bval[par][k] = (1.f + wp.z) * sg.z; } }
                    if (f3) { int k = atomicAdd(&s_bcnt[par], 1); if (k < BCAP) {
                              s_bidx[par][k] = n0 + 3; s_bval[par][k] = (1.f + wp.w) * sg.w; } }
                }
                RAWBAR();             // pushes + cnt visible
                int cnt = s_bcnt[par]; if (cnt > BCAP) cnt = BCAP;
                float4 syn = {0.f,0.f,0.f,0.f};
                if (__builtin_expect(cnt != 0, 0)) {   // rare secondary spikes
                    for (int m = 0; m < cnt; ++m) {
                        const int nm = s_bidx[par][m];
                        const float vm = s_bval[par][m];
                        const float4 wr = *(const float4*)(w + (size_t)nm * NN + n0);
                        syn.x = fmaf(vm, fabsf(wr.x), syn.x);
                        syn.y = fmaf(vm, fabsf(wr.y), syn.y);
                        syn.z = fmaf(vm, fabsf(wr.z), syn.z);
                        syn.w = fmaf(vm, fabsf(wr.w), syn.w);
                    }
                }
                if (tid < NOUT) {
                    float c = 0.f;
                    for (int m = 0; m < cnt; ++m)
                        c += w_out[(size_t)s_bidx[par][m] * NOUT + tid];
                    o2 = 0.9f * o2 + c;
                    outb[(size_t)(t0 + j) * NOUT] = o2;
                }
                mem.x = fmaf(0.9f, mem.x, a.x) + syn.x - (f0 ? 1.f : 0.f);
                mem.y = fmaf(0.9f, mem.y, a.y) + syn.y - (f1 ? 1.f : 0.f);
                mem.z = fmaf(0.9f, mem.z, a.z) + syn.z - (f2 ? 1.f : 0.f);
                mem.w = fmaf(0.9f, mem.w, a.w) + syn.w - (f3 ? 1.f : 0.f);
                wp.x = f0 ? 0.99f*wp.x + p4.x*(1.f + depr.x*wp.x) : 0.99f*wp.x;
                wp.y = f1 ? 0.99f*wp.y + p4.y*(1.f + depr.y*wp.y) : 0.99f*wp.y;
                wp.z = f2 ? 0.99f*wp.z + p4.z*(1.f + depr.z*wp.z) : 0.99f*wp.z;
                wp.w = f3 ? 0.99f*wp.w + p4.w*(1.f + depr.w*wp.w) : 0.99f*wp.w;
                if (__builtin_expect(cnt != 0, 0)) {
                    RAWBAR();         // all reads of B-list done
                    if (tid == 0) s_bcnt[par] = 0;
                }
                // cnt==0: nothing written, buffer already 0 -> no 2nd barrier
            }
        }
        RAWBAR();                     // all A-list reads done before reset
        if (tid < S) s_acnt[p][tid] = 0;
        else if (tid == S) s_amask[p] = 0;
    };

    for (int wnd = 0; wnd < NWIN - 1; wnd += 2) {
        window(PA, PB, wnd);
        window(PB, PA, wnd + 1);
    }
    window(PA, PB, NWIN - 1);   // NWIN-1 = 24 even -> cur is PA ✓
#undef CVT4
#undef RAWBAR
}

// ---------------- launch ----------------------------------------------------
extern "C" void kernel_launch(void* const* d_in, const int* in_sizes, int n_in,
                              void* d_out, int out_size, void* d_ws, size_t ws_size,
                              hipStream_t stream) {
    (void)in_sizes; (void)n_in; (void)out_size; (void)ws_size;
    const float* inputs  = (const float*)d_in[0];
    const float* w       = (const float*)d_in[1];
    const float* w_in    = (const float*)d_in[2];
    const float* w_out   = (const float*)d_in[3];
    const float* w_signs = (const float*)d_in[4];
    const float* p       = (const float*)d_in[5];
    float* out = (float*)d_out;

    const size_t H1B = (size_t)BB * TT * NN * 2;      // 52,428,800 (h1 fp16)
    const size_t APB = (size_t)800 * 4096 * 2;        //  6,553,600 (A packed)

    _Float16* h1 = (_Float16*)d_ws;
    ushort*   Ap = (ushort*)((char*)d_ws + H1B);
    ushort*   Bp = (ushort*)((char*)d_ws + H1B + APB);

    repack_ab<<<928, 256, 0, stream>>>(inputs, w_in, Ap, Bp);

    dim3 gg(NN / 128, (BB * TT) / 128);               // (16, 100)
    h1_mfma<<<gg, 256, 0, stream>>>(Ap, Bp, h1);

    snn_scan<<<BB, 512, 0, stream>>>(h1, w, w_signs, p, w_out, out);
}

// Round 17
// 81.349 us; speedup vs baseline: 1.0451x; 1.0451x over previous
//
#include <hip/hip_runtime.h>

#define BB   64
#define TT   200
#define NIN  128
#define NN   2048
#define NOUT 20

#define S    8      // speculation window (TT = 25 * S)
#define NWIN 25
#define ACAP 64     // spec spike list capacity per step
#define BCAP 128    // replay spike list capacity

typedef __attribute__((ext_vector_type(8))) short short8;
typedef __attribute__((ext_vector_type(4))) float f32x4;
typedef __attribute__((ext_vector_type(4))) _Float16 h16x4;

// ---- bf16 split: x = hi + lo + eps, |eps| <= 2^-18 |x| ----------------------
__device__ __forceinline__ void bf16split(float x, ushort& h, ushort& l) {
    unsigned u = __float_as_uint(x);
    unsigned hb = (u + 0x7FFFu + ((u >> 16) & 1u)) >> 16;
    h = (ushort)hb;
    float xh = __uint_as_float(hb << 16);
    float xl = x - xh;                      // exact
    unsigned v = __float_as_uint(xl);
    l = (ushort)((v + 0x7FFFu + ((v >> 16) & 1u)) >> 16);
}

// ---- merged pre-kernel: split+repack A and B^T into MFMA-fragment order ----
// Blocks 0..799: Ap [row_blk=800][kc=4][hl=2][lane=64][8] from inputs.
// Blocks 800..927: Bp [n_blk=128][kc=4][hl=2][lane=64][8] from w_in (transp.)
// Independent work -> one launch instead of two (saves a launch gap).
__global__ __launch_bounds__(256) void repack_ab(
    const float* __restrict__ X, const float* __restrict__ W,
    ushort* __restrict__ Ap, ushort* __restrict__ Bp)
{
    const int tid  = threadIdx.x;
    const int kc   = tid >> 6;
    const int lane = tid & 63;
    const int lr   = lane & 15, lg = lane >> 4;

    float f[8];
    ushort* dst;
    if (blockIdx.x < 800) {
        const int blk = blockIdx.x;         // row_blk 0..799
        const float* src = X + (size_t)(blk * 16 + lr) * NIN + kc * 32 + lg * 8;
        *(float4*)(f)     = *(const float4*)(src);
        *(float4*)(f + 4) = *(const float4*)(src + 4);
        dst = Ap + (size_t)(blk * 4 + kc) * 1024 + lane * 8;
    } else {
        const int blk = blockIdx.x - 800;   // n_blk 0..127
        const float* src = W + (size_t)(kc * 32 + lg * 8) * NN + blk * 16 + lr;
        #pragma unroll
        for (int j = 0; j < 8; ++j) f[j] = src[(size_t)j * NN];
        dst = Bp + (size_t)(blk * 4 + kc) * 1024 + lane * 8;
    }

    short8 hv, lv;
    #pragma unroll
    for (int j = 0; j < 8; ++j) {
        ushort h, l;
        bf16split(f[j], h, l);
        hv[j] = (short)h; lv[j] = (short)l;
    }
    *(short8*)(dst)       = hv;
    *(short8*)(dst + 512) = lv;
}

// ---- MFMA GEMM with per-kc LDS staging + fp16 epilogue (R10/R15, verified) --
// h1 = Ah*Bh + Ah*Bl + Al*Bh  (verified product set / chain order)
// Double-buffered 64KB LDS, 2 blocks/CU — best measured GEMM config (~32us).
__global__ __launch_bounds__(256, 2) void h1_mfma(
    const ushort* __restrict__ Ap, const ushort* __restrict__ Bp,
    _Float16* __restrict__ C)
{
    __shared__ ushort sbuf[2][16][1024];   // [dbuf][side*8+chunk][hl*512+lane*8]

    const int l   = blockIdx.y * gridDim.x + blockIdx.x;  // 0..1599
    const int nl  = (l & 7) * 200 + (l >> 3);             // bijective XCD chunk
    const int bx  = nl & 15, by = nl >> 4;

    const int tid  = threadIdx.x;
    const int w_   = tid >> 6, lane = tid & 63;
    const int lr   = lane & 15, lg = lane >> 4;
    const int m0   = by * 128, n0 = bx * 128;
    const int wr   = (w_ >> 1) * 64, wc = (w_ & 1) * 64;

    const ushort* pAs = Ap + (size_t)(m0 >> 4) * 4096;    // row_blk stride 4096
    const ushort* pBs = Bp + (size_t)(n0 >> 4) * 4096;

    // wave w_ stages (chunk,hl) pairs idx = w_*8 .. w_*8+7 of 32 total
#define STAGE(kc, nb)                                                        \
    do {                                                                     \
        _Pragma("unroll")                                                    \
        for (int i_ = 0; i_ < 8; ++i_) {                                     \
            const int idx_   = w_ * 8 + i_;                                  \
            const int side_  = idx_ >> 4;                                    \
            const int chunk_ = (idx_ >> 1) & 7;                              \
            const int hl_    = idx_ & 1;                                     \
            const ushort* g_ = (side_ ? pBs : pAs) + chunk_ * 4096           \
                               + (kc) * 1024 + hl_ * 512 + lane * 8;         \
            ushort* d_ = &sbuf[nb][idx_ >> 1][hl_ * 512];                    \
            __builtin_amdgcn_global_load_lds(                                \
                (const __attribute__((address_space(1))) void*)g_,           \
                (__attribute__((address_space(3))) void*)d_, 16, 0, 0);      \
        }                                                                    \
    } while (0)

    f32x4 acc[4][4];
    const f32x4 z = {0.f, 0.f, 0.f, 0.f};
    #pragma unroll
    for (int rb = 0; rb < 4; ++rb)
        #pragma unroll
        for (int cb = 0; cb < 4; ++cb) acc[rb][cb] = z;

    STAGE(0, 0);
    __syncthreads();    // drains vmcnt: stage(0) complete

    const int ar = wr >> 4;        // A chunk base (0 or 4)
    const int br = 8 + (wc >> 4);  // B chunk base (8 or 12)

    #pragma unroll
    for (int kc = 0; kc < 4; ++kc) {
        const int cb_ = kc & 1;
        if (kc < 3) STAGE(kc + 1, cb_ ^ 1);     // prefetch under compute

        short8 fah[4], fal[4], fbh[4], fbl[4];
        #pragma unroll
        for (int rb = 0; rb < 4; ++rb) {
            fah[rb] = *(const short8*)(&sbuf[cb_][ar + rb][lane * 8]);
            fal[rb] = *(const short8*)(&sbuf[cb_][ar + rb][512 + lane * 8]);
        }
        #pragma unroll
        for (int cb = 0; cb < 4; ++cb) {
            fbh[cb] = *(const short8*)(&sbuf[cb_][br + cb][lane * 8]);
            fbl[cb] = *(const short8*)(&sbuf[cb_][br + cb][512 + lane * 8]);
        }
        #pragma unroll
        for (int rb = 0; rb < 4; ++rb)
            #pragma unroll
            for (int cb = 0; cb < 4; ++cb) {
                acc[rb][cb] = __builtin_amdgcn_mfma_f32_16x16x32_bf16(
                    fbh[cb], fah[rb], acc[rb][cb], 0, 0, 0);
                acc[rb][cb] = __builtin_amdgcn_mfma_f32_16x16x32_bf16(
                    fbl[cb], fah[rb], acc[rb][cb], 0, 0, 0);
                acc[rb][cb] = __builtin_amdgcn_mfma_f32_16x16x32_bf16(
                    fbh[cb], fal[rb], acc[rb][cb], 0, 0, 0);
            }
        if (kc < 3) __syncthreads();   // stage(kc+1) done; buf[cb_] reads done
    }
#undef STAGE

    #pragma unroll
    for (int rb = 0; rb < 4; ++rb) {
        _Float16* Crow = C + (size_t)(m0 + wr + rb * 16 + lr) * NN
                           + n0 + wc + lg * 4;
        #pragma unroll
        for (int cb = 0; cb < 4; ++cb) {
            h16x4 hv;
            hv[0] = (_Float16)acc[rb][cb][0];
            hv[1] = (_Float16)acc[rb][cb][1];
            hv[2] = (_Float16)acc[rb][cb][2];
            hv[3] = (_Float16)acc[rb][cb][3];
            *(h16x4*)(Crow + cb * 16) = hv;
        }
    }
}

// ---------------- Phase 2+3: speculative windowed scan (R10 verbatim) --------
// 512 thr x 4 neurons, S=8. Slim dirty path (1-barrier cnt==0 steps, t* w-row
// prefetch). Verified 43-46us / VGPR 88.
__global__ __launch_bounds__(512) void snn_scan(
    const _Float16* __restrict__ h1, const float* __restrict__ w,
    const float* __restrict__ w_signs, const float* __restrict__ pvec,
    const float* __restrict__ w_out, float* __restrict__ out)
{
    const int b   = blockIdx.x;
    const int tid = threadIdx.x;
    const int n0  = tid << 2;

    __shared__ int   s_amask[2];
    __shared__ int   s_acnt[2][S];
    __shared__ int   s_aidx[2][S][ACAP];
    __shared__ float s_aval[2][S][ACAP];
    __shared__ int   s_bcnt[2];
    __shared__ int   s_bidx[2][BCAP];
    __shared__ float s_bval[2][BCAP];

    if (tid < 2) { s_amask[tid] = 0; s_bcnt[tid] = 0; }
    if (tid < 2 * S) ((int*)s_acnt)[tid] = 0;

    float4 mem = {0.f,0.f,0.f,0.f}, wp = {0.f,0.f,0.f,0.f};
    const float4 p4 = *(const float4*)(pvec + n0);
    const float4 sg = *(const float4*)(w_signs + n0);
    float4 depr;
    depr.x = (p4.x < 0.f) ? 1.f : 0.f;  depr.y = (p4.y < 0.f) ? 1.f : 0.f;
    depr.z = (p4.z < 0.f) ? 1.f : 0.f;  depr.w = (p4.w < 0.f) ? 1.f : 0.f;

    const float P99[S] = {1.0f, 0.99f, 0.9801f, 0.970299f, 0.96059601f,
                          0.9509900499f, 0.941480149401f, 0.93206534790699f};
    const float P99_8 = 0.9227446944279201f;

    const _Float16* hb = h1 + (size_t)b * TT * NN + n0;
    float* outb = out + (size_t)b * TT * NOUT + tid;   // used only if tid<20
    float o2 = 0.f;

    h16x4 PA[S], PB[S];
    #pragma unroll
    for (int j = 0; j < S; ++j) PA[j] = *(const h16x4*)(hb + (size_t)j * NN);
    __syncthreads();   // LDS init visible

#define RAWBAR()                                              \
    do { asm volatile("s_waitcnt lgkmcnt(0)" ::: "memory");   \
         __builtin_amdgcn_s_barrier();                        \
         asm volatile("" ::: "memory"); } while (0)

#define CVT4(v) { (float)(v)[0], (float)(v)[1], (float)(v)[2], (float)(v)[3] }

    auto window = [&](h16x4 (&Pc)[S], h16x4 (&Pf)[S], int wnd) {
        const int p  = wnd & 1;
        const int t0 = wnd * S;
        const float4 memB = mem, wpB = wp;

        // ---- slim speculative pass: syn = 0, wp frozen, no barriers ----
        #pragma unroll
        for (int j = 0; j < S; ++j) {
            const float4 a = CVT4(Pc[j]);
            int tp = t0 + j + S; if (tp > TT - 1) tp = TT - 1;
            Pf[j] = *(const h16x4*)(hb + (size_t)tp * NN);   // depth-1 fetch

            // spike test on PRE-update mem (reference semantics)
            const float mx = fmaxf(fmaxf(mem.x, mem.y), fmaxf(mem.z, mem.w));
            if (__builtin_expect(mx > 1.f, 0)) {
                const bool f0 = mem.x > 1.f, f1 = mem.y > 1.f,
                           f2 = mem.z > 1.f, f3 = mem.w > 1.f;
                atomicOr(&s_amask[p], 1 << j);
                if (f0) { int k = atomicAdd(&s_acnt[p][j], 1);
                          if (k < ACAP) { s_aidx[p][j][k] = n0;
                                          s_aval[p][j][k] = (1.f + wp.x * P99[j]) * sg.x; } }
                if (f1) { int k = atomicAdd(&s_acnt[p][j], 1);
                          if (k < ACAP) { s_aidx[p][j][k] = n0 + 1;
                                          s_aval[p][j][k] = (1.f + wp.y * P99[j]) * sg.y; } }
                if (f2) { int k = atomicAdd(&s_acnt[p][j], 1);
                          if (k < ACAP) { s_aidx[p][j][k] = n0 + 2;
                                          s_aval[p][j][k] = (1.f + wp.z * P99[j]) * sg.z; } }
                if (f3) { int k = atomicAdd(&s_acnt[p][j], 1);
                          if (k < ACAP) { s_aidx[p][j][k] = n0 + 3;
                                          s_aval[p][j][k] = (1.f + wp.w * P99[j]) * sg.w; } }
                mem.x = fmaf(0.9f, mem.x, a.x) - (f0 ? 1.f : 0.f);
                mem.y = fmaf(0.9f, mem.y, a.y) - (f1 ? 1.f : 0.f);
                mem.z = fmaf(0.9f, mem.z, a.z) - (f2 ? 1.f : 0.f);
                mem.w = fmaf(0.9f, mem.w, a.w) - (f3 ? 1.f : 0.f);
            } else {
                mem.x = fmaf(0.9f, mem.x, a.x);
                mem.y = fmaf(0.9f, mem.y, a.y);
                mem.z = fmaf(0.9f, mem.z, a.z);
                mem.w = fmaf(0.9f, mem.w, a.w);
            }
        }

        RAWBAR();                    // no vmcnt drain: prefetch stays in flight
        const int mask = s_amask[p];

        if (__builtin_expect(mask == 0, 1)) {   // ---- clean window ----
            wp.x *= P99_8; wp.y *= P99_8; wp.z *= P99_8; wp.w *= P99_8;
            if (tid < NOUT) {
                #pragma unroll
                for (int j = 0; j < S; ++j) {
                    o2 = 0.9f * o2;
                    outb[(size_t)(t0 + j) * NOUT] = o2;
                }
            }
            return;
        }

        // ---- dirty window: rollback + exact replay (slim sync) ----
        const int tstar = __ffs(mask) - 1;

        // prefetch t* w-rows early: list is exact & complete; hide gather
        // latency under the j<t* register replay. (cnt is block-uniform.)
        int cntS = s_acnt[p][tstar]; if (cntS > ACAP) cntS = ACAP;
        int   pidx[4];
        float pval[4];
        float4 wpre[4];
        #pragma unroll
        for (int m_ = 0; m_ < 4; ++m_) {
            if (m_ < cntS) {
                pidx[m_] = s_aidx[p][tstar][m_];
                pval[m_] = s_aval[p][tstar][m_];
                wpre[m_] = *(const float4*)(w + (size_t)pidx[m_] * NN + n0);
            }
        }

        mem = memB; wp = wpB;
        #pragma unroll
        for (int j = 0; j < S; ++j) {
            const float4 a = CVT4(Pc[j]);
            if (j < tstar) {          // certified spike-free
                mem.x = fmaf(0.9f, mem.x, a.x);
                mem.y = fmaf(0.9f, mem.y, a.y);
                mem.z = fmaf(0.9f, mem.z, a.z);
                mem.w = fmaf(0.9f, mem.w, a.w);
                wp.x *= 0.99f; wp.y *= 0.99f; wp.z *= 0.99f; wp.w *= 0.99f;
                if (tid < NOUT) { o2 = 0.9f * o2;
                                  outb[(size_t)(t0 + j) * NOUT] = o2; }
            } else if (j == tstar) {  // spec list at t* is exact & complete
                const bool f0 = mem.x > 1.f, f1 = mem.y > 1.f,   // pre-update
                           f2 = mem.z > 1.f, f3 = mem.w > 1.f;
                float4 syn = {0.f,0.f,0.f,0.f};
                #pragma unroll
                for (int m_ = 0; m_ < 4; ++m_) {
                    if (m_ < cntS) {
                        syn.x = fmaf(pval[m_], fabsf(wpre[m_].x), syn.x);
                        syn.y = fmaf(pval[m_], fabsf(wpre[m_].y), syn.y);
                        syn.z = fmaf(pval[m_], fabsf(wpre[m_].z), syn.z);
                        syn.w = fmaf(pval[m_], fabsf(wpre[m_].w), syn.w);
                    }
                }
                for (int m = 4; m < cntS; ++m) {
                    const int nm = s_aidx[p][tstar][m];
                    const float vm = s_aval[p][tstar][m];
                    const float4 wr = *(const float4*)(w + (size_t)nm * NN + n0);
                    syn.x = fmaf(vm, fabsf(wr.x), syn.x);
                    syn.y = fmaf(vm, fabsf(wr.y), syn.y);
                    syn.z = fmaf(vm, fabsf(wr.z), syn.z);
                    syn.w = fmaf(vm, fabsf(wr.w), syn.w);
                }
                if (tid < NOUT) {
                    float c = 0.f;
                    for (int m = 0; m < cntS; ++m)
                        c += w_out[(size_t)s_aidx[p][tstar][m] * NOUT + tid];
                    o2 = 0.9f * o2 + c;
                    outb[(size_t)(t0 + j) * NOUT] = o2;
                }
                mem.x = fmaf(0.9f, mem.x, a.x) + syn.x - (f0 ? 1.f : 0.f);
                mem.y = fmaf(0.9f, mem.y, a.y) + syn.y - (f1 ? 1.f : 0.f);
                mem.z = fmaf(0.9f, mem.z, a.z) + syn.z - (f2 ? 1.f : 0.f);
                mem.w = fmaf(0.9f, mem.w, a.w) + syn.w - (f3 ? 1.f : 0.f);
                wp.x = f0 ? 0.99f*wp.x + p4.x*(1.f + depr.x*wp.x) : 0.99f*wp.x;
                wp.y = f1 ? 0.99f*wp.y + p4.y*(1.f + depr.y*wp.y) : 0.99f*wp.y;
                wp.z = f2 ? 0.99f*wp.z + p4.z*(1.f + depr.z*wp.z) : 0.99f*wp.z;
                wp.w = f3 ? 0.99f*wp.w + p4.w*(1.f + depr.w*wp.w) : 0.99f*wp.w;
            } else {                  // slow step: 1 barrier; exchange only if
                                      // spikes actually landed this step
                const int par = j & 1;
                const bool f0 = mem.x > 1.f, f1 = mem.y > 1.f,   // pre-update
                           f2 = mem.z > 1.f, f3 = mem.w > 1.f;
                if (f0 | f1 | f2 | f3) {
                    if (f0) { int k = atomicAdd(&s_bcnt[par], 1); if (k < BCAP) {
                              s_bidx[par][k] = n0;     s_bval[par][k] = (1.f + wp.x) * sg.x; } }
                    if (f1) { int k = atomicAdd(&s_bcnt[par], 1); if (k < BCAP) {
                              s_bidx[par][k] = n0 + 1; s_bval[par][k] = (1.f + wp.y) * sg.y; } }
                    if (f2) { int k = atomicAdd(&s_bcnt[par], 1); if (k < BCAP) {
                              s_bidx[par][k] = n0 + 2; s_bval[par][k] = (1.f + wp.z) * sg.z; } }
                    if (f3) { int k = atomicAdd(&s_bcnt[par], 1); if (k < BCAP) {
                              s_bidx[par][k] = n0 + 3; s_bval[par][k] = (1.f + wp.w) * sg.w; } }
                }
                RAWBAR();             // pushes + cnt visible
                int cnt = s_bcnt[par]; if (cnt > BCAP) cnt = BCAP;
                float4 syn = {0.f,0.f,0.f,0.f};
                if (__builtin_expect(cnt != 0, 0)) {   // rare secondary spikes
                    for (int m = 0; m < cnt; ++m) {
                        const int nm = s_bidx[par][m];
                        const float vm = s_bval[par][m];
                        const float4 wr = *(const float4*)(w + (size_t)nm * NN + n0);
                        syn.x = fmaf(vm, fabsf(wr.x), syn.x);
                        syn.y = fmaf(vm, fabsf(wr.y), syn.y);
                        syn.z = fmaf(vm, fabsf(wr.z), syn.z);
                        syn.w = fmaf(vm, fabsf(wr.w), syn.w);
                    }
                }
                if (tid < NOUT) {
                    float c = 0.f;
                    for (int m = 0; m < cnt; ++m)
                        c += w_out[(size_t)s_bidx[par][m] * NOUT + tid];
                    o2 = 0.9f * o2 + c;
                    outb[(size_t)(t0 + j) * NOUT] = o2;
                }
                mem.x = fmaf(0.9f, mem.x, a.x) + syn.x - (f0 ? 1.f : 0.f);
                mem.y = fmaf(0.9f, mem.y, a.y) + syn.y - (f1 ? 1.f : 0.f);
                mem.z = fmaf(0.9f, mem.z, a.z) + syn.z - (f2 ? 1.f : 0.f);
                mem.w = fmaf(0.9f, mem.w, a.w) + syn.w - (f3 ? 1.f : 0.f);
                wp.x = f0 ? 0.99f*wp.x + p4.x*(1.f + depr.x*wp.x) : 0.99f*wp.x;
                wp.y = f1 ? 0.99f*wp.y + p4.y*(1.f + depr.y*wp.y) : 0.99f*wp.y;
                wp.z = f2 ? 0.99f*wp.z + p4.z*(1.f + depr.z*wp.z) : 0.99f*wp.z;
                wp.w = f3 ? 0.99f*wp.w + p4.w*(1.f + depr.w*wp.w) : 0.99f*wp.w;
                if (__builtin_expect(cnt != 0, 0)) {
                    RAWBAR();         // all reads of B-list done
                    if (tid == 0) s_bcnt[par] = 0;
                }
                // cnt==0: nothing written, buffer already 0 -> no 2nd barrier
            }
        }
        RAWBAR();                     // all A-list reads done before reset
        if (tid < S) s_acnt[p][tid] = 0;
        else if (tid == S) s_amask[p] = 0;
    };

    for (int wnd = 0; wnd < NWIN - 1; wnd += 2) {
        window(PA, PB, wnd);
        window(PB, PA, wnd + 1);
    }
    window(PA, PB, NWIN - 1);   // NWIN-1 = 24 even -> cur is PA ✓
#undef CVT4
#undef RAWBAR
}

// ---------------- launch ----------------------------------------------------
extern "C" void kernel_launch(void* const* d_in, const int* in_sizes, int n_in,
                              void* d_out, int out_size, void* d_ws, size_t ws_size,
                              hipStream_t stream) {
    (void)in_sizes; (void)n_in; (void)out_size; (void)ws_size;
    const float* inputs  = (const float*)d_in[0];
    const float* w       = (const float*)d_in[1];
    const float* w_in    = (const float*)d_in[2];
    const float* w_out   = (const float*)d_in[3];
    const float* w_signs = (const float*)d_in[4];
    const float* p       = (const float*)d_in[5];
    float* out = (float*)d_out;

    const size_t H1B = (size_t)BB * TT * NN * 2;      // 52,428,800 (h1 fp16)
    const size_t APB = (size_t)800 * 4096 * 2;        //  6,553,600 (A packed)

    _Float16* h1 = (_Float16*)d_ws;
    ushort*   Ap = (ushort*)((char*)d_ws + H1B);
    ushort*   Bp = (ushort*)((char*)d_ws + H1B + APB);

    repack_ab<<<928, 256, 0, stream>>>(inputs, w_in, Ap, Bp);

    dim3 gg(NN / 128, (BB * TT) / 128);               // (16, 100)
    h1_mfma<<<gg, 256, 0, stream>>>(Ap, Bp, h1);

    snn_scan<<<BB, 512, 0, stream>>>(h1, w, w_signs, p, w_out, out);
}